// Round 13
// baseline (342.571 us; speedup 1.0000x reference)
//
#include <hip/hip_runtime.h>

#define N_NODES 100000
#define N_EDGES 800000
#define N_LABEL 400000
// IN_CH = 256, OUT_CH = 256, H1 = 128, H2 = 32
// Key algebra: b_gcn cancels in h[dst]-h[src]; h@W1 = S_hat (x @ (W_gcn@W1)).
// So we only ever need p = S_hat(x@Wf) [100k,128], Wf = W_gcn@W1.
// qs GEMM and edge-MLP layer2 run on MFMA via split-bf16:
// C = Ah@Bh + Ah@Bl + Al@Bh (lo*lo dropped, ~2^-18 relative).

typedef __attribute__((ext_vector_type(8))) short bf16x8;
typedef __attribute__((ext_vector_type(4))) float f32x4;
typedef unsigned int uint;
typedef unsigned short ushort;

__device__ __forceinline__ ushort f2bf(float f) {  // round-to-nearest-even
    uint u = __float_as_uint(f);
    u += 0x7FFFu + ((u >> 16) & 1u);
    return (ushort)(u >> 16);
}
__device__ __forceinline__ uint pack2(ushort a, ushort b) {
    return (uint)a | ((uint)b << 16);
}

// ---------------- init counters ----------------
__global__ void k_zero2(int* __restrict__ a, int* __restrict__ b) {
    int i = blockIdx.x * 256 + threadIdx.x;
    if (i < N_NODES) { a[i] = 0; b[i] = 0; }
}

__global__ void k_count(const int* __restrict__ ei, int* __restrict__ cnt) {
    int e = blockIdx.x * 256 + threadIdx.x;
    if (e < N_EDGES) atomicAdd(&cnt[ei[N_EDGES + e]], 1);  // dst = ei[1][e]
}

// ---------------- hierarchical exclusive scan: cnt -> rowptr (+dis) --------
__global__ __launch_bounds__(1024) void k_bsum(const int* __restrict__ cnt,
                                               int* __restrict__ bsum) {
    __shared__ int red[1024];
    int t = threadIdx.x;
    int i = blockIdx.x * 1024 + t;
    red[t] = (i < N_NODES) ? cnt[i] : 0;
    __syncthreads();
    #pragma unroll
    for (int off = 512; off; off >>= 1) {
        if (t < off) red[t] += red[t + off];
        __syncthreads();
    }
    if (t == 0) bsum[blockIdx.x] = red[0];
}

__global__ void k_bscan(int* __restrict__ bsum, int nb) {
    __shared__ int s[128];
    int t = threadIdx.x;
    s[t] = (t < nb) ? bsum[t] : 0;
    __syncthreads();
    #pragma unroll
    for (int off = 1; off < 128; off <<= 1) {
        int v = (t >= off) ? s[t - off] : 0;
        __syncthreads();
        s[t] += v;
        __syncthreads();
    }
    if (t < nb) bsum[t] = t ? s[t - 1] : 0;
}

// also computes dis[i] = rsqrt(deg+1) (folded k_dis: saves one launch)
__global__ __launch_bounds__(1024) void k_rowptr(const int* __restrict__ cnt,
                                                 const int* __restrict__ bsum,
                                                 int* __restrict__ rowptr,
                                                 float* __restrict__ dis) {
    __shared__ int s[1024];
    int t = threadIdx.x;
    int i = blockIdx.x * 1024 + t;
    int v = (i < N_NODES) ? cnt[i] : 0;
    s[t] = v;
    __syncthreads();
    #pragma unroll
    for (int off = 1; off < 1024; off <<= 1) {
        int u = (t >= off) ? s[t - off] : 0;
        __syncthreads();
        s[t] += u;
        __syncthreads();
    }
    int excl = s[t] - v + bsum[blockIdx.x];
    if (i < N_NODES) {
        rowptr[i] = excl;
        dis[i] = rsqrtf((float)(v + 1));  // +1 self loop
    }
    if (i == N_NODES - 1) rowptr[N_NODES] = excl + v;  // == N_EDGES
}

__global__ void k_fill(const int* __restrict__ ei, const int* __restrict__ rowptr,
                       int* __restrict__ cursor, int* __restrict__ csr) {
    int e = blockIdx.x * 256 + threadIdx.x;
    if (e >= N_EDGES) return;
    int src = ei[e];
    int dst = ei[N_EDGES + e];
    int pos = rowptr[dst] + atomicAdd(&cursor[dst], 1);
    csr[pos] = src;
}

// ---------------- fp32 tiled GEMM (only for tiny Wf = Wg@W1) ----------------
__global__ __launch_bounds__(256) void gemm_f32(
    const float* __restrict__ A, const float* __restrict__ B,
    float* __restrict__ C, int M, int N, int K,
    const float* __restrict__ rowscale) {
    __shared__ float As[2][16][132];
    __shared__ float Bs[2][16][132];

    const int tid = threadIdx.x;
    const int tx = tid & 15, ty = tid >> 4;
    const int m0 = blockIdx.x * 128, n0 = blockIdx.y * 128;

    const int ar = tid >> 2;
    const int ac = (tid & 3) * 4;
    const int bk = tid >> 5;
    const int bc = (tid & 31) * 4;

    float acc[8][8] = {};
    float4 va[2], vb[2];

    auto loadG = [&](int k0) {
        #pragma unroll
        for (int hh = 0; hh < 2; ++hh) {
            int row = m0 + ar + hh * 64;
            va[hh] = make_float4(0.f, 0.f, 0.f, 0.f);
            if (row < M) va[hh] = *(const float4*)&A[(size_t)row * K + k0 + ac];
            vb[hh] = *(const float4*)&B[(size_t)(k0 + bk + hh * 8) * N + n0 + bc];
        }
    };
    auto storeL = [&](int buf) {
        #pragma unroll
        for (int hh = 0; hh < 2; ++hh) {
            As[buf][ac + 0][ar + hh * 64] = va[hh].x;
            As[buf][ac + 1][ar + hh * 64] = va[hh].y;
            As[buf][ac + 2][ar + hh * 64] = va[hh].z;
            As[buf][ac + 3][ar + hh * 64] = va[hh].w;
            *(float4*)&Bs[buf][bk + hh * 8][bc] = vb[hh];
        }
    };

    loadG(0);
    storeL(0);
    __syncthreads();

    int cur = 0;
    for (int k0 = 16;; k0 += 16) {
        const bool last = (k0 >= K);
        if (!last) loadG(k0);

        #pragma unroll
        for (int kk = 0; kk < 16; ++kk) {
            const float4 a0 = *(const float4*)&As[cur][kk][ty * 8];
            const float4 a1 = *(const float4*)&As[cur][kk][ty * 8 + 4];
            const float4 b0 = *(const float4*)&Bs[cur][kk][tx * 8];
            const float4 b1 = *(const float4*)&Bs[cur][kk][tx * 8 + 4];
            const float aa[8] = {a0.x, a0.y, a0.z, a0.w, a1.x, a1.y, a1.z, a1.w};
            const float bb[8] = {b0.x, b0.y, b0.z, b0.w, b1.x, b1.y, b1.z, b1.w};
            #pragma unroll
            for (int i = 0; i < 8; ++i)
                #pragma unroll
                for (int j = 0; j < 8; ++j)
                    acc[i][j] = fmaf(aa[i], bb[j], acc[i][j]);
        }
        if (last) break;
        storeL(cur ^ 1);
        __syncthreads();
        cur ^= 1;
    }

    #pragma unroll
    for (int i = 0; i < 8; ++i) {
        int row = m0 + ty * 8 + i;
        if (row < M) {
            float s = rowscale ? rowscale[row] : 1.0f;
            float4 c0 = {acc[i][0] * s, acc[i][1] * s, acc[i][2] * s, acc[i][3] * s};
            float4 c1 = {acc[i][4] * s, acc[i][5] * s, acc[i][6] * s, acc[i][7] * s};
            *(float4*)&C[(size_t)row * N + n0 + tx * 8] = c0;
            *(float4*)&C[(size_t)row * N + n0 + tx * 8 + 4] = c1;
        }
    }
}

// ---------------- Wf -> bf16 hi/lo, fragment-linear for MFMA B-operand ------
__global__ void k_wsplit(const float* __restrict__ Wf, ushort* __restrict__ Bh,
                         ushort* __restrict__ Bl) {
    int id = blockIdx.x * 256 + threadIdx.x;
    if (id >= 32768) return;
    int j = id & 7, l = (id >> 3) & 63, ct = (id >> 9) & 7, s = id >> 12;
    int k = s * 32 + (l >> 4) * 8 + j;
    int col = ct * 16 + (l & 15);
    float w = Wf[k * 128 + col];
    ushort h = f2bf(w);
    float hf = __uint_as_float(((uint)h) << 16);
    ushort lo = f2bf(w - hf);
    Bh[id] = h;
    Bl[id] = lo;
}

// ---------------- W2 -> bf16 hi/lo, fragment-linear (for edge-MLP layer2) ---
__global__ void k_w2split(const float* __restrict__ W2, ushort* __restrict__ W2h,
                          ushort* __restrict__ W2l) {
    int id = blockIdx.x * 256 + threadIdx.x;
    if (id >= 4096) return;
    int j = id & 7, l = (id >> 3) & 63, ct = (id >> 9) & 1, s = id >> 10;
    int k = s * 32 + (l >> 4) * 8 + j;
    int col = ct * 16 + (l & 15);
    float w = W2[k * 32 + col];
    ushort h = f2bf(w);
    float hf = __uint_as_float(((uint)h) << 16);
    ushort lo = f2bf(w - hf);
    W2h[id] = h;
    W2l[id] = lo;
}

// ---------------- MFMA split-bf16 GEMM: qs = (x @ Wf) * dis[row] ------------
__global__ __launch_bounds__(256) void gemm_mfma(
    const float* __restrict__ x, const ushort* __restrict__ Bh,
    const ushort* __restrict__ Bl, const float* __restrict__ dis,
    float* __restrict__ qs) {
    __shared__ __align__(16) ushort Ah[4096], Al[4096], Bhs[4096], Bls[4096];

    const int tid = threadIdx.x;
    const int w = tid >> 6, lane = tid & 63;
    const int m0 = blockIdx.x * 128;
    const int srow = tid >> 3;   // 0..31: row within 32-row staging pass
    const int skq = tid & 7;     // k-quad: covers k = skq*4 .. skq*4+3

    f32x4 acc[2][8];
    #pragma unroll
    for (int i = 0; i < 2; ++i)
        #pragma unroll
        for (int j = 0; j < 8; ++j)
            acc[i][j] = (f32x4){0.f, 0.f, 0.f, 0.f};

    float4 r0, r1, r2, r3;       // x prefetch: pass p covers rows p*32+srow
    uint4 pb0, pb1, pc0, pc1;    // B prefetch (hi: pb, lo: pc)

    auto xload = [&](int s) {
        const int kc = s * 32 + skq * 4;
        int row;
        const float4 z = make_float4(0.f, 0.f, 0.f, 0.f);
        row = m0 + srow;       r0 = (row < N_NODES) ? *(const float4*)&x[(size_t)row * 256 + kc] : z;
        row = m0 + 32 + srow;  r1 = (row < N_NODES) ? *(const float4*)&x[(size_t)row * 256 + kc] : z;
        row = m0 + 64 + srow;  r2 = (row < N_NODES) ? *(const float4*)&x[(size_t)row * 256 + kc] : z;
        row = m0 + 96 + srow;  r3 = (row < N_NODES) ? *(const float4*)&x[(size_t)row * 256 + kc] : z;
    };
    auto bload = [&](int s) {
        const uint4* ph = (const uint4*)(Bh + s * 4096);
        const uint4* pl = (const uint4*)(Bl + s * 4096);
        pb0 = ph[tid * 2]; pb1 = ph[tid * 2 + 1];
        pc0 = pl[tid * 2]; pc1 = pl[tid * 2 + 1];
    };
    auto stageA = [&](int p, const float4& v) {
        const int off = ((p * 2 + (srow >> 4)) * 64 + (skq >> 1) * 16 + (srow & 15)) * 8
                        + (skq & 1) * 4;
        ushort h0 = f2bf(v.x), h1 = f2bf(v.y), h2 = f2bf(v.z), h3 = f2bf(v.w);
        *(uint2*)&Ah[off] = make_uint2(pack2(h0, h1), pack2(h2, h3));
        float l0 = v.x - __uint_as_float(((uint)h0) << 16);
        float l1 = v.y - __uint_as_float(((uint)h1) << 16);
        float l2 = v.z - __uint_as_float(((uint)h2) << 16);
        float l3 = v.w - __uint_as_float(((uint)h3) << 16);
        *(uint2*)&Al[off] = make_uint2(pack2(f2bf(l0), f2bf(l1)),
                                       pack2(f2bf(l2), f2bf(l3)));
    };

    xload(0);
    bload(0);

    for (int s = 0; s < 8; ++s) {
        if (s) __syncthreads();
        stageA(0, r0); stageA(1, r1); stageA(2, r2); stageA(3, r3);
        *(uint4*)&Bhs[tid * 16] = pb0; *(uint4*)&Bhs[tid * 16 + 8] = pb1;
        *(uint4*)&Bls[tid * 16] = pc0; *(uint4*)&Bls[tid * 16 + 8] = pc1;
        if (s < 7) { xload(s + 1); bload(s + 1); }
        __syncthreads();

        const bf16x8 ah0 = *(const bf16x8*)&Ah[((w * 2 + 0) * 64 + lane) * 8];
        const bf16x8 al0 = *(const bf16x8*)&Al[((w * 2 + 0) * 64 + lane) * 8];
        const bf16x8 ah1 = *(const bf16x8*)&Ah[((w * 2 + 1) * 64 + lane) * 8];
        const bf16x8 al1 = *(const bf16x8*)&Al[((w * 2 + 1) * 64 + lane) * 8];
        #pragma unroll
        for (int ct = 0; ct < 8; ++ct) {
            const bf16x8 bh = *(const bf16x8*)&Bhs[(ct * 64 + lane) * 8];
            const bf16x8 bl = *(const bf16x8*)&Bls[(ct * 64 + lane) * 8];
            acc[0][ct] = __builtin_amdgcn_mfma_f32_16x16x32_bf16(al0, bh, acc[0][ct], 0, 0, 0);
            acc[0][ct] = __builtin_amdgcn_mfma_f32_16x16x32_bf16(ah0, bl, acc[0][ct], 0, 0, 0);
            acc[0][ct] = __builtin_amdgcn_mfma_f32_16x16x32_bf16(ah0, bh, acc[0][ct], 0, 0, 0);
            acc[1][ct] = __builtin_amdgcn_mfma_f32_16x16x32_bf16(al1, bh, acc[1][ct], 0, 0, 0);
            acc[1][ct] = __builtin_amdgcn_mfma_f32_16x16x32_bf16(ah1, bl, acc[1][ct], 0, 0, 0);
            acc[1][ct] = __builtin_amdgcn_mfma_f32_16x16x32_bf16(ah1, bh, acc[1][ct], 0, 0, 0);
        }
    }

    #pragma unroll
    for (int rt = 0; rt < 2; ++rt) {
        #pragma unroll
        for (int j = 0; j < 4; ++j) {
            const int row = m0 + w * 32 + rt * 16 + (lane >> 4) * 4 + j;
            if (row < N_NODES) {
                const float sc = dis[row];
                #pragma unroll
                for (int ct = 0; ct < 8; ++ct)
                    qs[(size_t)row * 128 + ct * 16 + (lane & 15)] = acc[rt][ct][j] * sc;
            }
        }
    }
}

// ---------------- CSR gather v3: 8 independent row loads in flight ----------
__global__ __launch_bounds__(256) void k_gather(
    const float* __restrict__ qs, const int* __restrict__ rowptr,
    const int* __restrict__ csr, const float* __restrict__ dis,
    float* __restrict__ p) {
    int node = blockIdx.x * 4 + (threadIdx.x >> 6);
    if (node >= N_NODES) return;
    int lane = threadIdx.x & 63;
    int beg = rowptr[node], end = rowptr[node + 1];
    float2 acc = *(const float2*)&qs[(size_t)node * 128 + lane * 2];
    int j = beg;
    for (; j + 8 <= end; j += 8) {
        int s0 = csr[j],     s1 = csr[j + 1], s2 = csr[j + 2], s3 = csr[j + 3];
        int s4 = csr[j + 4], s5 = csr[j + 5], s6 = csr[j + 6], s7 = csr[j + 7];
        float2 v0 = *(const float2*)&qs[(size_t)s0 * 128 + lane * 2];
        float2 v1 = *(const float2*)&qs[(size_t)s1 * 128 + lane * 2];
        float2 v2 = *(const float2*)&qs[(size_t)s2 * 128 + lane * 2];
        float2 v3 = *(const float2*)&qs[(size_t)s3 * 128 + lane * 2];
        float2 v4 = *(const float2*)&qs[(size_t)s4 * 128 + lane * 2];
        float2 v5 = *(const float2*)&qs[(size_t)s5 * 128 + lane * 2];
        float2 v6 = *(const float2*)&qs[(size_t)s6 * 128 + lane * 2];
        float2 v7 = *(const float2*)&qs[(size_t)s7 * 128 + lane * 2];
        acc.x += v0.x; acc.y += v0.y;  acc.x += v1.x; acc.y += v1.y;
        acc.x += v2.x; acc.y += v2.y;  acc.x += v3.x; acc.y += v3.y;
        acc.x += v4.x; acc.y += v4.y;  acc.x += v5.x; acc.y += v5.y;
        acc.x += v6.x; acc.y += v6.y;  acc.x += v7.x; acc.y += v7.y;
    }
    for (; j + 4 <= end; j += 4) {
        int s0 = csr[j], s1 = csr[j + 1], s2 = csr[j + 2], s3 = csr[j + 3];
        float2 v0 = *(const float2*)&qs[(size_t)s0 * 128 + lane * 2];
        float2 v1 = *(const float2*)&qs[(size_t)s1 * 128 + lane * 2];
        float2 v2 = *(const float2*)&qs[(size_t)s2 * 128 + lane * 2];
        float2 v3 = *(const float2*)&qs[(size_t)s3 * 128 + lane * 2];
        acc.x += v0.x; acc.y += v0.y;  acc.x += v1.x; acc.y += v1.y;
        acc.x += v2.x; acc.y += v2.y;  acc.x += v3.x; acc.y += v3.y;
    }
    for (; j < end; ++j) {
        int src = csr[j];
        float2 v = *(const float2*)&qs[(size_t)src * 128 + lane * 2];
        acc.x += v.x;
        acc.y += v.y;
    }
    float d = dis[node];
    float2 r = {acc.x * d, acc.y * d};
    *(float2*)&p[(size_t)node * 128 + lane * 2] = r;
}

// ---------------- fused edge MLP v8: 8 waves/block, sequential hi/lo --------
// v7 was occupancy-capped (48KB LDS, 4 waves -> 12 waves/CU, measured 25%).
// v8: 512 threads (8 waves); staging LDS halved by staging only the hi tile
// (4KB/wave) and keeping lo packed in 8 named uint2 regs: run 16 hi-MFMAs,
// overwrite tile with lo (same-wave DS pipe is in-order), run 8 lo-MFMAs.
// LDS = 8*4KB + 16KB(W2) = 48KB -> 3 blocks x 8 waves = 24 waves/CU (75%).
// Grid 782 blocks ~= one resident generation. All arrays static-indexed.
__global__ __launch_bounds__(512, 4) void k_edge_mlp(
    const float* __restrict__ p, const int* __restrict__ eli,
    const float* __restrict__ b1, const ushort* __restrict__ W2h,
    const ushort* __restrict__ W2l, const float* __restrict__ b2,
    const float* __restrict__ W3, const float* __restrict__ b3,
    float* __restrict__ out) {
    __shared__ __align__(16) ushort sth[8][2048];
    __shared__ __align__(16) ushort w2hs[4096], w2ls[4096];

    const int tid = threadIdx.x;
    const int wave = tid >> 6, lane = tid & 63;
    const int row = lane & 15;   // edge within a 16-edge batch
    const int s = lane >> 4;     // channel group: s*32 .. s*32+31

    // stage W2 fragments to LDS (once per block): 512 threads x 8 ushorts
    *(uint4*)&w2hs[tid * 8] = *(const uint4*)&W2h[tid * 8];
    *(uint4*)&w2ls[tid * 8] = *(const uint4*)&W2l[tid * 8];
    __syncthreads();

    const int e0 = (blockIdx.x * 8 + wave) * 64;  // 4 batches x 16 edges

    // eli for all 4 batches up front (clamped; OOB batches skip the write)
    int srcs[4], dsts[4];
    #pragma unroll
    for (int b = 0; b < 4; ++b) {
        const int eb = (e0 + b * 16 < N_LABEL) ? e0 + b * 16 : 0;
        srcs[b] = eli[eb + row];
        dsts[b] = eli[N_LABEL + eb + row];
    }

    const float b2a = b2[row];
    const float b2b = b2[16 + row];
    const float w3a = W3[row];
    const float w3b = W3[16 + row];
    const float b3r = b3[0];

    float4 pdb[2][8], psb[2][8];
    auto loadrows = [&](int b, int buf) {
        const float* prd = &p[(size_t)dsts[b] * 128 + s * 32];
        const float* prs = &p[(size_t)srcs[b] * 128 + s * 32];
        #pragma unroll
        for (int cc = 0; cc < 8; ++cc) {
            pdb[buf][cc] = *(const float4*)&prd[cc * 4];
            psb[buf][cc] = *(const float4*)&prs[cc * 4];
        }
    };

    loadrows(0, 0);

    #pragma unroll
    for (int b = 0; b < 4; ++b) {
        const int cur = b & 1;
        // layer1: hi -> LDS tile; lo -> packed named regs (static-indexed)
        uint2 loq[8];
        #pragma unroll
        for (int cc = 0; cc < 8; ++cc) {
            const float4 pd = pdb[cur][cc];
            const float4 ps = psb[cur][cc];
            const float4 bb = *(const float4*)&b1[s * 32 + cc * 4];
            float t0 = fmaxf(pd.x - ps.x + bb.x, 0.f);
            float t1 = fmaxf(pd.y - ps.y + bb.y, 0.f);
            float t2 = fmaxf(pd.z - ps.z + bb.z, 0.f);
            float t3 = fmaxf(pd.w - ps.w + bb.w, 0.f);
            ushort h0 = f2bf(t0), h1 = f2bf(t1), h2 = f2bf(t2), h3 = f2bf(t3);
            const int off = (s * 64 + (cc >> 1) * 16 + row) * 8 + (cc & 1) * 4;
            *(uint2*)&sth[wave][off] = make_uint2(pack2(h0, h1), pack2(h2, h3));
            float l0 = t0 - __uint_as_float(((uint)h0) << 16);
            float l1 = t1 - __uint_as_float(((uint)h1) << 16);
            float l2 = t2 - __uint_as_float(((uint)h2) << 16);
            float l3 = t3 - __uint_as_float(((uint)h3) << 16);
            loq[cc] = make_uint2(pack2(f2bf(l0), f2bf(l1)),
                                 pack2(f2bf(l2), f2bf(l3)));
        }
        // prefetch next batch's rows (flies under the MFMA passes below)
        if (b < 3) loadrows(b + 1, cur ^ 1);

        // pass A: hi MFMAs (Ah@Bh + Ah@Bl), A from per-wave LDS tile
        f32x4 acc0 = (f32x4){0.f, 0.f, 0.f, 0.f};
        f32x4 acc1 = (f32x4){0.f, 0.f, 0.f, 0.f};
        #pragma unroll
        for (int ss = 0; ss < 4; ++ss) {
            const bf16x8 ah = *(const bf16x8*)&sth[wave][(ss * 64 + lane) * 8];
            const bf16x8 bh0 = *(const bf16x8*)&w2hs[((ss * 2 + 0) * 64 + lane) * 8];
            const bf16x8 bl0 = *(const bf16x8*)&w2ls[((ss * 2 + 0) * 64 + lane) * 8];
            const bf16x8 bh1 = *(const bf16x8*)&w2hs[((ss * 2 + 1) * 64 + lane) * 8];
            const bf16x8 bl1 = *(const bf16x8*)&w2ls[((ss * 2 + 1) * 64 + lane) * 8];
            acc0 = __builtin_amdgcn_mfma_f32_16x16x32_bf16(ah, bh0, acc0, 0, 0, 0);
            acc0 = __builtin_amdgcn_mfma_f32_16x16x32_bf16(ah, bl0, acc0, 0, 0, 0);
            acc1 = __builtin_amdgcn_mfma_f32_16x16x32_bf16(ah, bh1, acc1, 0, 0, 0);
            acc1 = __builtin_amdgcn_mfma_f32_16x16x32_bf16(ah, bl1, acc1, 0, 0, 0);
        }
        // overwrite tile with lo (same-wave DS ops are in-order; compiler
        // sees the alias and keeps read-before-write order)
        #pragma unroll
        for (int cc = 0; cc < 8; ++cc) {
            const int off = (s * 64 + (cc >> 1) * 16 + row) * 8 + (cc & 1) * 4;
            *(uint2*)&sth[wave][off] = loq[cc];
        }
        // pass B: lo MFMAs (Al@Bh)
        #pragma unroll
        for (int ss = 0; ss < 4; ++ss) {
            const bf16x8 al = *(const bf16x8*)&sth[wave][(ss * 64 + lane) * 8];
            const bf16x8 bh0 = *(const bf16x8*)&w2hs[((ss * 2 + 0) * 64 + lane) * 8];
            const bf16x8 bh1 = *(const bf16x8*)&w2hs[((ss * 2 + 1) * 64 + lane) * 8];
            acc0 = __builtin_amdgcn_mfma_f32_16x16x32_bf16(al, bh0, acc0, 0, 0, 0);
            acc1 = __builtin_amdgcn_mfma_f32_16x16x32_bf16(al, bh1, acc1, 0, 0, 0);
        }

        // epilogue: u = relu(acc + b2); out_row = sum_col u*W3[col] + b3
        // D: out-row(edge) = s*4 + j, col = ct*16 + (lane&15)
        const bool wr = (e0 + b * 16) < N_LABEL;
        #pragma unroll
        for (int j = 0; j < 4; ++j) {
            float v = fmaxf(acc0[j] + b2a, 0.f) * w3a
                    + fmaxf(acc1[j] + b2b, 0.f) * w3b;
            v += __shfl_xor(v, 1);
            v += __shfl_xor(v, 2);
            v += __shfl_xor(v, 4);
            v += __shfl_xor(v, 8);
            if (wr && row == 0) out[e0 + b * 16 + s * 4 + j] = v + b3r;
        }
    }
}

// ---------------- launch ----------------
extern "C" void kernel_launch(void* const* d_in, const int* in_sizes, int n_in,
                              void* d_out, int out_size, void* d_ws, size_t ws_size,
                              hipStream_t stream) {
    const float* x   = (const float*)d_in[0];
    const int*   ei  = (const int*)d_in[1];
    const int*   eli = (const int*)d_in[2];
    const float* Wg  = (const float*)d_in[3];
    // d_in[4] = b_gcn : cancels in h[dst]-h[src], unused
    const float* W1  = (const float*)d_in[5];
    const float* b1  = (const float*)d_in[6];
    const float* W2  = (const float*)d_in[7];
    const float* b2  = (const float*)d_in[8];
    const float* W3  = (const float*)d_in[9];
    const float* b3  = (const float*)d_in[10];
    float* out = (float*)d_out;

    // ---- workspace layout (bytes), all regions disjoint & 16B-aligned ----
    char* ws = (char*)d_ws;
    float*  dis    = (float*)(ws + 0);           // 400 KB
    int*    cnt    = (int*)(ws + 524288);        // 400 KB
    int*    cursor = (int*)(ws + 1048576);       // 400 KB
    int*    rowptr = (int*)(ws + 1572864);       // 400 KB + 4
    int*    bsum   = (int*)(ws + 2000000);       // 512 B (98 ints)
    int*    csr    = (int*)(ws + 2097152);       // 3.2 MB (4 MB reserved)
    float*  Wf     = (float*)(ws + 6291456);     // 128 KB
    ushort* Bh     = (ushort*)(ws + 6422528);    // 64 KB
    ushort* Bl     = (ushort*)(ws + 6488064);    // 64 KB
    ushort* W2h    = (ushort*)(ws + 6553600);    // 8 KB
    ushort* W2l    = (ushort*)(ws + 6561792);    // 8 KB
    float*  qs     = (float*)(ws + 8388608);     // 51.2 MB
    float*  p      = (float*)(ws + 59588608);    // 51.2 MB

    const int NB = (N_NODES + 1023) / 1024;      // 98

    // CSR build + degree norm
    k_zero2<<<(N_NODES + 255) / 256, 256, 0, stream>>>(cnt, cursor);
    k_count<<<(N_EDGES + 255) / 256, 256, 0, stream>>>(ei, cnt);
    k_bsum<<<NB, 1024, 0, stream>>>(cnt, bsum);
    k_bscan<<<1, 128, 0, stream>>>(bsum, NB);
    k_rowptr<<<NB, 1024, 0, stream>>>(cnt, bsum, rowptr, dis);
    k_fill<<<(N_EDGES + 255) / 256, 256, 0, stream>>>(ei, rowptr, cursor, csr);

    // Wf = W_gcn @ W1   [256,256]@[256,128]  (tiny, stays fp32)
    gemm_f32<<<dim3(2, 1), 256, 0, stream>>>(Wg, W1, Wf, 256, 128, 256, nullptr);

    // weight splits (tiny)
    k_wsplit<<<128, 256, 0, stream>>>(Wf, Bh, Bl);
    k_w2split<<<16, 256, 0, stream>>>(W2, W2h, W2l);

    // qs = (x @ Wf) * dis[row]  via split-bf16 MFMA
    gemm_mfma<<<(N_NODES + 127) / 128, 256, 0, stream>>>(x, Bh, Bl, dis, qs);

    // p[i] = dis[i] * (qs[i] + sum_{src->i} qs[src])
    k_gather<<<(N_NODES + 3) / 4, 256, 0, stream>>>(qs, rowptr, csr, dis, p);

    // fused per-edge MLP: 8 waves x 4 batches x 16 edges = 512 edges/block
    k_edge_mlp<<<(N_LABEL + 511) / 512, 512, 0, stream>>>(
        p, eli, b1, W2h, W2l, b2, W3, b3, out);
}

// Round 14
// 299.408 us; speedup vs baseline: 1.1442x; 1.1442x over previous
//
#include <hip/hip_runtime.h>

#define N_NODES 100000
#define N_EDGES 800000
#define N_LABEL 400000
// IN_CH = 256, OUT_CH = 256, H1 = 128, H2 = 32
// Key algebra: b_gcn cancels in h[dst]-h[src]; h@W1 = S_hat (x @ (W_gcn@W1)).
// So we only ever need p = S_hat(x@Wf) [100k,128], Wf = W_gcn@W1.
// qs GEMM and edge-MLP layer2 run on MFMA via split-bf16:
// C = Ah@Bh + Ah@Bl + Al@Bh (lo*lo dropped, ~2^-18 relative).

typedef __attribute__((ext_vector_type(8))) short bf16x8;
typedef __attribute__((ext_vector_type(4))) float f32x4;
typedef unsigned int uint;
typedef unsigned short ushort;

__device__ __forceinline__ ushort f2bf(float f) {  // round-to-nearest-even
    uint u = __float_as_uint(f);
    u += 0x7FFFu + ((u >> 16) & 1u);
    return (ushort)(u >> 16);
}
__device__ __forceinline__ uint pack2(ushort a, ushort b) {
    return (uint)a | ((uint)b << 16);
}

// ---------------- init counters ----------------
__global__ void k_zero2(int* __restrict__ a, int* __restrict__ b) {
    int i = blockIdx.x * 256 + threadIdx.x;
    if (i < N_NODES) { a[i] = 0; b[i] = 0; }
}

__global__ void k_count(const int* __restrict__ ei, int* __restrict__ cnt) {
    int e = blockIdx.x * 256 + threadIdx.x;
    if (e < N_EDGES) atomicAdd(&cnt[ei[N_EDGES + e]], 1);  // dst = ei[1][e]
}

// ---------------- hierarchical exclusive scan: cnt -> rowptr (+dis) --------
__global__ __launch_bounds__(1024) void k_bsum(const int* __restrict__ cnt,
                                               int* __restrict__ bsum) {
    __shared__ int red[1024];
    int t = threadIdx.x;
    int i = blockIdx.x * 1024 + t;
    red[t] = (i < N_NODES) ? cnt[i] : 0;
    __syncthreads();
    #pragma unroll
    for (int off = 512; off; off >>= 1) {
        if (t < off) red[t] += red[t + off];
        __syncthreads();
    }
    if (t == 0) bsum[blockIdx.x] = red[0];
}

__global__ void k_bscan(int* __restrict__ bsum, int nb) {
    __shared__ int s[128];
    int t = threadIdx.x;
    s[t] = (t < nb) ? bsum[t] : 0;
    __syncthreads();
    #pragma unroll
    for (int off = 1; off < 128; off <<= 1) {
        int v = (t >= off) ? s[t - off] : 0;
        __syncthreads();
        s[t] += v;
        __syncthreads();
    }
    if (t < nb) bsum[t] = t ? s[t - 1] : 0;
}

// also computes dis[i] = rsqrt(deg+1) (folded k_dis)
__global__ __launch_bounds__(1024) void k_rowptr(const int* __restrict__ cnt,
                                                 const int* __restrict__ bsum,
                                                 int* __restrict__ rowptr,
                                                 float* __restrict__ dis) {
    __shared__ int s[1024];
    int t = threadIdx.x;
    int i = blockIdx.x * 1024 + t;
    int v = (i < N_NODES) ? cnt[i] : 0;
    s[t] = v;
    __syncthreads();
    #pragma unroll
    for (int off = 1; off < 1024; off <<= 1) {
        int u = (t >= off) ? s[t - off] : 0;
        __syncthreads();
        s[t] += u;
        __syncthreads();
    }
    int excl = s[t] - v + bsum[blockIdx.x];
    if (i < N_NODES) {
        rowptr[i] = excl;
        dis[i] = rsqrtf((float)(v + 1));  // +1 self loop
    }
    if (i == N_NODES - 1) rowptr[N_NODES] = excl + v;  // == N_EDGES
}

__global__ void k_fill(const int* __restrict__ ei, const int* __restrict__ rowptr,
                       int* __restrict__ cursor, int* __restrict__ csr) {
    int e = blockIdx.x * 256 + threadIdx.x;
    if (e >= N_EDGES) return;
    int src = ei[e];
    int dst = ei[N_EDGES + e];
    int pos = rowptr[dst] + atomicAdd(&cursor[dst], 1);
    csr[pos] = src;
}

// ---------------- fused Wf=Wg@W1 + hi/lo split + W2 split (one kernel) ------
// blockIdx < 128: Wf fragment id = blockIdx*256+tid (32768 outputs, each an
// independent 256-dot over L2-resident weights). blockIdx >= 128: W2 split.
// Replaces the 2-block gemm_f32 (latency-bound on 2 CUs) + 2 split launches.
__global__ __launch_bounds__(256) void k_wf_split(
    const float* __restrict__ Wg, const float* __restrict__ W1,
    const float* __restrict__ W2, ushort* __restrict__ Bh,
    ushort* __restrict__ Bl, ushort* __restrict__ W2h,
    ushort* __restrict__ W2l) {
    const int tid = threadIdx.x;
    if (blockIdx.x < 128) {
        const int id = blockIdx.x * 256 + tid;
        const int j = id & 7, l = (id >> 3) & 63, ct = (id >> 9) & 7, s = id >> 12;
        const int k = s * 32 + (l >> 4) * 8 + j;
        const int col = ct * 16 + (l & 15);
        const float* wgrow = &Wg[k * 256];
        float w = 0.f;
        #pragma unroll 4
        for (int b = 0; b < 256; b += 4) {
            const float4 g = *(const float4*)&wgrow[b];
            w = fmaf(g.x, W1[(b + 0) * 128 + col], w);
            w = fmaf(g.y, W1[(b + 1) * 128 + col], w);
            w = fmaf(g.z, W1[(b + 2) * 128 + col], w);
            w = fmaf(g.w, W1[(b + 3) * 128 + col], w);
        }
        ushort h = f2bf(w);
        float hf = __uint_as_float(((uint)h) << 16);
        Bh[id] = h;
        Bl[id] = f2bf(w - hf);
    } else {
        const int id = (blockIdx.x - 128) * 256 + tid;  // < 4096
        const int j = id & 7, l = (id >> 3) & 63, ct = (id >> 9) & 1, s = id >> 10;
        const int k = s * 32 + (l >> 4) * 8 + j;
        const int col = ct * 16 + (l & 15);
        float w = W2[k * 32 + col];
        ushort h = f2bf(w);
        float hf = __uint_as_float(((uint)h) << 16);
        W2h[id] = h;
        W2l[id] = f2bf(w - hf);
    }
}

// ---------------- MFMA split-bf16 GEMM: qs = (x @ Wf) * dis[row] ------------
__global__ __launch_bounds__(256) void gemm_mfma(
    const float* __restrict__ x, const ushort* __restrict__ Bh,
    const ushort* __restrict__ Bl, const float* __restrict__ dis,
    float* __restrict__ qs) {
    __shared__ __align__(16) ushort Ah[4096], Al[4096], Bhs[4096], Bls[4096];

    const int tid = threadIdx.x;
    const int w = tid >> 6, lane = tid & 63;
    const int m0 = blockIdx.x * 128;
    const int srow = tid >> 3;   // 0..31: row within 32-row staging pass
    const int skq = tid & 7;     // k-quad: covers k = skq*4 .. skq*4+3

    f32x4 acc[2][8];
    #pragma unroll
    for (int i = 0; i < 2; ++i)
        #pragma unroll
        for (int j = 0; j < 8; ++j)
            acc[i][j] = (f32x4){0.f, 0.f, 0.f, 0.f};

    float4 r0, r1, r2, r3;       // x prefetch: pass p covers rows p*32+srow
    uint4 pb0, pb1, pc0, pc1;    // B prefetch (hi: pb, lo: pc)

    auto xload = [&](int s) {
        const int kc = s * 32 + skq * 4;
        int row;
        const float4 z = make_float4(0.f, 0.f, 0.f, 0.f);
        row = m0 + srow;       r0 = (row < N_NODES) ? *(const float4*)&x[(size_t)row * 256 + kc] : z;
        row = m0 + 32 + srow;  r1 = (row < N_NODES) ? *(const float4*)&x[(size_t)row * 256 + kc] : z;
        row = m0 + 64 + srow;  r2 = (row < N_NODES) ? *(const float4*)&x[(size_t)row * 256 + kc] : z;
        row = m0 + 96 + srow;  r3 = (row < N_NODES) ? *(const float4*)&x[(size_t)row * 256 + kc] : z;
    };
    auto bload = [&](int s) {
        const uint4* ph = (const uint4*)(Bh + s * 4096);
        const uint4* pl = (const uint4*)(Bl + s * 4096);
        pb0 = ph[tid * 2]; pb1 = ph[tid * 2 + 1];
        pc0 = pl[tid * 2]; pc1 = pl[tid * 2 + 1];
    };
    auto stageA = [&](int p, const float4& v) {
        const int off = ((p * 2 + (srow >> 4)) * 64 + (skq >> 1) * 16 + (srow & 15)) * 8
                        + (skq & 1) * 4;
        ushort h0 = f2bf(v.x), h1 = f2bf(v.y), h2 = f2bf(v.z), h3 = f2bf(v.w);
        *(uint2*)&Ah[off] = make_uint2(pack2(h0, h1), pack2(h2, h3));
        float l0 = v.x - __uint_as_float(((uint)h0) << 16);
        float l1 = v.y - __uint_as_float(((uint)h1) << 16);
        float l2 = v.z - __uint_as_float(((uint)h2) << 16);
        float l3 = v.w - __uint_as_float(((uint)h3) << 16);
        *(uint2*)&Al[off] = make_uint2(pack2(f2bf(l0), f2bf(l1)),
                                       pack2(f2bf(l2), f2bf(l3)));
    };

    xload(0);
    bload(0);

    for (int s = 0; s < 8; ++s) {
        if (s) __syncthreads();
        stageA(0, r0); stageA(1, r1); stageA(2, r2); stageA(3, r3);
        *(uint4*)&Bhs[tid * 16] = pb0; *(uint4*)&Bhs[tid * 16 + 8] = pb1;
        *(uint4*)&Bls[tid * 16] = pc0; *(uint4*)&Bls[tid * 16 + 8] = pc1;
        if (s < 7) { xload(s + 1); bload(s + 1); }
        __syncthreads();

        const bf16x8 ah0 = *(const bf16x8*)&Ah[((w * 2 + 0) * 64 + lane) * 8];
        const bf16x8 al0 = *(const bf16x8*)&Al[((w * 2 + 0) * 64 + lane) * 8];
        const bf16x8 ah1 = *(const bf16x8*)&Ah[((w * 2 + 1) * 64 + lane) * 8];
        const bf16x8 al1 = *(const bf16x8*)&Al[((w * 2 + 1) * 64 + lane) * 8];
        #pragma unroll
        for (int ct = 0; ct < 8; ++ct) {
            const bf16x8 bh = *(const bf16x8*)&Bhs[(ct * 64 + lane) * 8];
            const bf16x8 bl = *(const bf16x8*)&Bls[(ct * 64 + lane) * 8];
            acc[0][ct] = __builtin_amdgcn_mfma_f32_16x16x32_bf16(al0, bh, acc[0][ct], 0, 0, 0);
            acc[0][ct] = __builtin_amdgcn_mfma_f32_16x16x32_bf16(ah0, bl, acc[0][ct], 0, 0, 0);
            acc[0][ct] = __builtin_amdgcn_mfma_f32_16x16x32_bf16(ah0, bh, acc[0][ct], 0, 0, 0);
            acc[1][ct] = __builtin_amdgcn_mfma_f32_16x16x32_bf16(al1, bh, acc[1][ct], 0, 0, 0);
            acc[1][ct] = __builtin_amdgcn_mfma_f32_16x16x32_bf16(ah1, bl, acc[1][ct], 0, 0, 0);
            acc[1][ct] = __builtin_amdgcn_mfma_f32_16x16x32_bf16(ah1, bh, acc[1][ct], 0, 0, 0);
        }
    }

    #pragma unroll
    for (int rt = 0; rt < 2; ++rt) {
        #pragma unroll
        for (int j = 0; j < 4; ++j) {
            const int row = m0 + w * 32 + rt * 16 + (lane >> 4) * 4 + j;
            if (row < N_NODES) {
                const float sc = dis[row];
                #pragma unroll
                for (int ct = 0; ct < 8; ++ct)
                    qs[(size_t)row * 128 + ct * 16 + (lane & 15)] = acc[rt][ct][j] * sc;
            }
        }
    }
}

// ---------------- CSR gather v4: 2 nodes/wave, float4 lanes, 8-deep ILP -----
__global__ __launch_bounds__(256) void k_gather(
    const float* __restrict__ qs, const int* __restrict__ rowptr,
    const int* __restrict__ csr, const float* __restrict__ dis,
    float* __restrict__ p) {
    int node = blockIdx.x * 8 + (threadIdx.x >> 5);  // half-wave per node
    if (node >= N_NODES) return;
    int sl = threadIdx.x & 31;                       // 32 lanes x 16B = row
    int beg = rowptr[node], end = rowptr[node + 1];
    float4 acc = *(const float4*)&qs[(size_t)node * 128 + sl * 4];
    int j = beg;
    for (; j + 8 <= end; j += 8) {
        int s0 = csr[j],     s1 = csr[j + 1], s2 = csr[j + 2], s3 = csr[j + 3];
        int s4 = csr[j + 4], s5 = csr[j + 5], s6 = csr[j + 6], s7 = csr[j + 7];
        float4 v0 = *(const float4*)&qs[(size_t)s0 * 128 + sl * 4];
        float4 v1 = *(const float4*)&qs[(size_t)s1 * 128 + sl * 4];
        float4 v2 = *(const float4*)&qs[(size_t)s2 * 128 + sl * 4];
        float4 v3 = *(const float4*)&qs[(size_t)s3 * 128 + sl * 4];
        float4 v4 = *(const float4*)&qs[(size_t)s4 * 128 + sl * 4];
        float4 v5 = *(const float4*)&qs[(size_t)s5 * 128 + sl * 4];
        float4 v6 = *(const float4*)&qs[(size_t)s6 * 128 + sl * 4];
        float4 v7 = *(const float4*)&qs[(size_t)s7 * 128 + sl * 4];
        acc.x += v0.x + v1.x + v2.x + v3.x + v4.x + v5.x + v6.x + v7.x;
        acc.y += v0.y + v1.y + v2.y + v3.y + v4.y + v5.y + v6.y + v7.y;
        acc.z += v0.z + v1.z + v2.z + v3.z + v4.z + v5.z + v6.z + v7.z;
        acc.w += v0.w + v1.w + v2.w + v3.w + v4.w + v5.w + v6.w + v7.w;
    }
    for (; j + 4 <= end; j += 4) {
        int s0 = csr[j], s1 = csr[j + 1], s2 = csr[j + 2], s3 = csr[j + 3];
        float4 v0 = *(const float4*)&qs[(size_t)s0 * 128 + sl * 4];
        float4 v1 = *(const float4*)&qs[(size_t)s1 * 128 + sl * 4];
        float4 v2 = *(const float4*)&qs[(size_t)s2 * 128 + sl * 4];
        float4 v3 = *(const float4*)&qs[(size_t)s3 * 128 + sl * 4];
        acc.x += v0.x + v1.x + v2.x + v3.x;
        acc.y += v0.y + v1.y + v2.y + v3.y;
        acc.z += v0.z + v1.z + v2.z + v3.z;
        acc.w += v0.w + v1.w + v2.w + v3.w;
    }
    for (; j < end; ++j) {
        int src = csr[j];
        float4 v = *(const float4*)&qs[(size_t)src * 128 + sl * 4];
        acc.x += v.x; acc.y += v.y; acc.z += v.z; acc.w += v.w;
    }
    float d = dis[node];
    float4 r = {acc.x * d, acc.y * d, acc.z * d, acc.w * d};
    *(float4*)&p[(size_t)node * 128 + sl * 4] = r;
}

// ---------------- fused edge MLP v7 (PROVEN 85us — v8's 8-wave seq-hi/lo
// variant regressed to 95.6us, occupancy didn't rise; do not re-try) --------
__global__ __launch_bounds__(256, 4) void k_edge_mlp(
    const float* __restrict__ p, const int* __restrict__ eli,
    const float* __restrict__ b1, const ushort* __restrict__ W2h,
    const ushort* __restrict__ W2l, const float* __restrict__ b2,
    const float* __restrict__ W3, const float* __restrict__ b3,
    float* __restrict__ out) {
    __shared__ __align__(16) ushort sth[4][2048], stl[4][2048];
    __shared__ __align__(16) ushort w2hs[4096], w2ls[4096];

    const int tid = threadIdx.x;
    const int wave = tid >> 6, lane = tid & 63;
    const int row = lane & 15;   // edge within a 16-edge batch
    const int s = lane >> 4;     // channel group: s*32 .. s*32+31

    // stage W2 fragments to LDS (once per block)
    *(uint4*)&w2hs[tid * 16]     = *(const uint4*)&W2h[tid * 16];
    *(uint4*)&w2hs[tid * 16 + 8] = *(const uint4*)&W2h[tid * 16 + 8];
    *(uint4*)&w2ls[tid * 16]     = *(const uint4*)&W2l[tid * 16];
    *(uint4*)&w2ls[tid * 16 + 8] = *(const uint4*)&W2l[tid * 16 + 8];
    __syncthreads();

    const int e0 = (blockIdx.x * 4 + wave) * 64;  // 4 batches x 16 edges

    int srcs[4], dsts[4];
    #pragma unroll
    for (int b = 0; b < 4; ++b) {
        const int eb = (e0 + b * 16 < N_LABEL) ? e0 + b * 16 : 0;
        srcs[b] = eli[eb + row];
        dsts[b] = eli[N_LABEL + eb + row];
    }

    const float b2a = b2[row];
    const float b2b = b2[16 + row];
    const float w3a = W3[row];
    const float w3b = W3[16 + row];
    const float b3r = b3[0];

    float4 pdb[2][8], psb[2][8];
    auto loadrows = [&](int b, int buf) {
        const float* prd = &p[(size_t)dsts[b] * 128 + s * 32];
        const float* prs = &p[(size_t)srcs[b] * 128 + s * 32];
        #pragma unroll
        for (int cc = 0; cc < 8; ++cc) {
            pdb[buf][cc] = *(const float4*)&prd[cc * 4];
            psb[buf][cc] = *(const float4*)&prs[cc * 4];
        }
    };

    loadrows(0, 0);

    #pragma unroll
    for (int b = 0; b < 4; ++b) {
        const int cur = b & 1;
        // layer1: t = relu(pd-ps+b1) -> hi/lo bf16 -> fragment-linear LDS
        #pragma unroll
        for (int cc = 0; cc < 8; ++cc) {
            const float4 pd = pdb[cur][cc];
            const float4 ps = psb[cur][cc];
            const float4 bb = *(const float4*)&b1[s * 32 + cc * 4];
            float t0 = fmaxf(pd.x - ps.x + bb.x, 0.f);
            float t1 = fmaxf(pd.y - ps.y + bb.y, 0.f);
            float t2 = fmaxf(pd.z - ps.z + bb.z, 0.f);
            float t3 = fmaxf(pd.w - ps.w + bb.w, 0.f);
            ushort h0 = f2bf(t0), h1 = f2bf(t1), h2 = f2bf(t2), h3 = f2bf(t3);
            const int off = (s * 64 + (cc >> 1) * 16 + row) * 8 + (cc & 1) * 4;
            *(uint2*)&sth[wave][off] = make_uint2(pack2(h0, h1), pack2(h2, h3));
            float l0 = t0 - __uint_as_float(((uint)h0) << 16);
            float l1 = t1 - __uint_as_float(((uint)h1) << 16);
            float l2 = t2 - __uint_as_float(((uint)h2) << 16);
            float l3 = t3 - __uint_as_float(((uint)h3) << 16);
            *(uint2*)&stl[wave][off] = make_uint2(pack2(f2bf(l0), f2bf(l1)),
                                                  pack2(f2bf(l2), f2bf(l3)));
        }
        // prefetch next batch's rows (flies under MFMA + epilogue below)
        if (b < 3) loadrows(b + 1, cur ^ 1);

        // layer2 on MFMA; A from per-wave LDS, B (W2) from block LDS
        f32x4 acc0 = (f32x4){0.f, 0.f, 0.f, 0.f};
        f32x4 acc1 = (f32x4){0.f, 0.f, 0.f, 0.f};
        #pragma unroll
        for (int ss = 0; ss < 4; ++ss) {
            const bf16x8 ah = *(const bf16x8*)&sth[wave][(ss * 64 + lane) * 8];
            const bf16x8 al = *(const bf16x8*)&stl[wave][(ss * 64 + lane) * 8];
            const bf16x8 bh0 = *(const bf16x8*)&w2hs[((ss * 2 + 0) * 64 + lane) * 8];
            const bf16x8 bl0 = *(const bf16x8*)&w2ls[((ss * 2 + 0) * 64 + lane) * 8];
            const bf16x8 bh1 = *(const bf16x8*)&w2hs[((ss * 2 + 1) * 64 + lane) * 8];
            const bf16x8 bl1 = *(const bf16x8*)&w2ls[((ss * 2 + 1) * 64 + lane) * 8];
            acc0 = __builtin_amdgcn_mfma_f32_16x16x32_bf16(al, bh0, acc0, 0, 0, 0);
            acc0 = __builtin_amdgcn_mfma_f32_16x16x32_bf16(ah, bl0, acc0, 0, 0, 0);
            acc0 = __builtin_amdgcn_mfma_f32_16x16x32_bf16(ah, bh0, acc0, 0, 0, 0);
            acc1 = __builtin_amdgcn_mfma_f32_16x16x32_bf16(al, bh1, acc1, 0, 0, 0);
            acc1 = __builtin_amdgcn_mfma_f32_16x16x32_bf16(ah, bl1, acc1, 0, 0, 0);
            acc1 = __builtin_amdgcn_mfma_f32_16x16x32_bf16(ah, bh1, acc1, 0, 0, 0);
        }

        // epilogue: u = relu(acc + b2); out_row = sum_col u*W3[col] + b3
        const bool wr = (e0 + b * 16) < N_LABEL;
        #pragma unroll
        for (int j = 0; j < 4; ++j) {
            float v = fmaxf(acc0[j] + b2a, 0.f) * w3a
                    + fmaxf(acc1[j] + b2b, 0.f) * w3b;
            v += __shfl_xor(v, 1);
            v += __shfl_xor(v, 2);
            v += __shfl_xor(v, 4);
            v += __shfl_xor(v, 8);
            if (wr && row == 0) out[e0 + b * 16 + s * 4 + j] = v + b3r;
        }
    }
}

// ---------------- launch ----------------
extern "C" void kernel_launch(void* const* d_in, const int* in_sizes, int n_in,
                              void* d_out, int out_size, void* d_ws, size_t ws_size,
                              hipStream_t stream) {
    const float* x   = (const float*)d_in[0];
    const int*   ei  = (const int*)d_in[1];
    const int*   eli = (const int*)d_in[2];
    const float* Wg  = (const float*)d_in[3];
    // d_in[4] = b_gcn : cancels in h[dst]-h[src], unused
    const float* W1  = (const float*)d_in[5];
    const float* b1  = (const float*)d_in[6];
    const float* W2  = (const float*)d_in[7];
    const float* b2  = (const float*)d_in[8];
    const float* W3  = (const float*)d_in[9];
    const float* b3  = (const float*)d_in[10];
    float* out = (float*)d_out;

    // ---- workspace layout (bytes), all regions disjoint & 16B-aligned ----
    char* ws = (char*)d_ws;
    float*  dis    = (float*)(ws + 0);           // 400 KB
    int*    cnt    = (int*)(ws + 524288);        // 400 KB
    int*    cursor = (int*)(ws + 1048576);       // 400 KB
    int*    rowptr = (int*)(ws + 1572864);       // 400 KB + 4
    int*    bsum   = (int*)(ws + 2000000);       // 512 B (98 ints)
    int*    csr    = (int*)(ws + 2097152);       // 3.2 MB (4 MB reserved)
    ushort* Bh     = (ushort*)(ws + 6422528);    // 64 KB
    ushort* Bl     = (ushort*)(ws + 6488064);    // 64 KB
    ushort* W2h    = (ushort*)(ws + 6553600);    // 8 KB
    ushort* W2l    = (ushort*)(ws + 6561792);    // 8 KB
    float*  qs     = (float*)(ws + 8388608);     // 51.2 MB
    float*  p      = (float*)(ws + 59588608);    // 51.2 MB

    const int NB = (N_NODES + 1023) / 1024;      // 98

    // CSR build + degree norm
    k_zero2<<<(N_NODES + 255) / 256, 256, 0, stream>>>(cnt, cursor);
    k_count<<<(N_EDGES + 255) / 256, 256, 0, stream>>>(ei, cnt);
    k_bsum<<<NB, 1024, 0, stream>>>(cnt, bsum);
    k_bscan<<<1, 128, 0, stream>>>(bsum, NB);
    k_rowptr<<<NB, 1024, 0, stream>>>(cnt, bsum, rowptr, dis);
    k_fill<<<(N_EDGES + 255) / 256, 256, 0, stream>>>(ei, rowptr, cursor, csr);

    // Wf = Wg@W1 -> hi/lo split, plus W2 split (one fused kernel)
    k_wf_split<<<144, 256, 0, stream>>>(Wg, W1, W2, Bh, Bl, W2h, W2l);

    // qs = (x @ Wf) * dis[row]  via split-bf16 MFMA
    gemm_mfma<<<(N_NODES + 127) / 128, 256, 0, stream>>>(x, Bh, Bl, dis, qs);

    // p[i] = dis[i] * (qs[i] + sum_{src->i} qs[src])  (2 nodes/wave)
    k_gather<<<(N_NODES + 7) / 8, 256, 0, stream>>>(qs, rowptr, csr, dis, p);

    // fused per-edge MLP v7: 4 waves x 4 batches x 16 edges = 256 edges/block
    k_edge_mlp<<<(N_LABEL + 255) / 256, 256, 0, stream>>>(
        p, eli, b1, W2h, W2l, b2, W3, b3, out);
}

// Round 15
// 299.384 us; speedup vs baseline: 1.1443x; 1.0001x over previous
//
#include <hip/hip_runtime.h>

#define N_NODES 100000
#define N_EDGES 800000
#define N_LABEL 400000
// IN_CH = 256, OUT_CH = 256, H1 = 128, H2 = 32
// Key algebra: b_gcn cancels in h[dst]-h[src]; h@W1 = S_hat (x @ (W_gcn@W1)).
// So we only ever need p = S_hat(x@Wf) [100k,128], Wf = W_gcn@W1.
// qs GEMM and edge-MLP layer2 run on MFMA via split-bf16:
// C = Ah@Bh + Ah@Bl + Al@Bh (lo*lo dropped, ~2^-18 relative).

typedef __attribute__((ext_vector_type(8))) short bf16x8;
typedef __attribute__((ext_vector_type(4))) float f32x4;
typedef unsigned int uint;
typedef unsigned short ushort;

__device__ __forceinline__ ushort f2bf(float f) {  // round-to-nearest-even
    uint u = __float_as_uint(f);
    u += 0x7FFFu + ((u >> 16) & 1u);
    return (ushort)(u >> 16);
}
__device__ __forceinline__ uint pack2(ushort a, ushort b) {
    return (uint)a | ((uint)b << 16);
}

// ---------------- degree count ----------------
__global__ void k_count(const int* __restrict__ ei, int* __restrict__ cnt) {
    int e = blockIdx.x * 256 + threadIdx.x;
    if (e < N_EDGES) atomicAdd(&cnt[ei[N_EDGES + e]], 1);  // dst = ei[1][e]
}

// ---------------- hierarchical exclusive scan: cnt -> rowptr (+dis,cursor) --
__global__ __launch_bounds__(1024) void k_bsum(const int* __restrict__ cnt,
                                               int* __restrict__ bsum) {
    __shared__ int red[1024];
    int t = threadIdx.x;
    int i = blockIdx.x * 1024 + t;
    red[t] = (i < N_NODES) ? cnt[i] : 0;
    __syncthreads();
    #pragma unroll
    for (int off = 512; off; off >>= 1) {
        if (t < off) red[t] += red[t + off];
        __syncthreads();
    }
    if (t == 0) bsum[blockIdx.x] = red[0];
}

__global__ void k_bscan(int* __restrict__ bsum, int nb) {
    __shared__ int s[128];
    int t = threadIdx.x;
    s[t] = (t < nb) ? bsum[t] : 0;
    __syncthreads();
    #pragma unroll
    for (int off = 1; off < 128; off <<= 1) {
        int v = (t >= off) ? s[t - off] : 0;
        __syncthreads();
        s[t] += v;
        __syncthreads();
    }
    if (t < nb) bsum[t] = t ? s[t - 1] : 0;
}

// also computes dis[i] = rsqrt(deg+1) and zeroes cursor (folded launches)
__global__ __launch_bounds__(1024) void k_rowptr(const int* __restrict__ cnt,
                                                 const int* __restrict__ bsum,
                                                 int* __restrict__ rowptr,
                                                 float* __restrict__ dis,
                                                 int* __restrict__ cursor) {
    __shared__ int s[1024];
    int t = threadIdx.x;
    int i = blockIdx.x * 1024 + t;
    int v = (i < N_NODES) ? cnt[i] : 0;
    s[t] = v;
    __syncthreads();
    #pragma unroll
    for (int off = 1; off < 1024; off <<= 1) {
        int u = (t >= off) ? s[t - off] : 0;
        __syncthreads();
        s[t] += u;
        __syncthreads();
    }
    int excl = s[t] - v + bsum[blockIdx.x];
    if (i < N_NODES) {
        rowptr[i] = excl;
        dis[i] = rsqrtf((float)(v + 1));  // +1 self loop
        cursor[i] = 0;
    }
    if (i == N_NODES - 1) rowptr[N_NODES] = excl + v;  // == N_EDGES
}

__global__ void k_fill(const int* __restrict__ ei, const int* __restrict__ rowptr,
                       int* __restrict__ cursor, int* __restrict__ csr) {
    int e = blockIdx.x * 256 + threadIdx.x;
    if (e >= N_EDGES) return;
    int src = ei[e];
    int dst = ei[N_EDGES + e];
    int pos = rowptr[dst] + atomicAdd(&cursor[dst], 1);
    csr[pos] = src;
}

// ---------------- fused Wf=Wg@W1 + hi/lo split + W2 split (one kernel) ------
__global__ __launch_bounds__(256) void k_wf_split(
    const float* __restrict__ Wg, const float* __restrict__ W1,
    const float* __restrict__ W2, ushort* __restrict__ Bh,
    ushort* __restrict__ Bl, ushort* __restrict__ W2h,
    ushort* __restrict__ W2l) {
    const int tid = threadIdx.x;
    if (blockIdx.x < 128) {
        const int id = blockIdx.x * 256 + tid;
        const int j = id & 7, l = (id >> 3) & 63, ct = (id >> 9) & 7, s = id >> 12;
        const int k = s * 32 + (l >> 4) * 8 + j;
        const int col = ct * 16 + (l & 15);
        const float* wgrow = &Wg[k * 256];
        float w = 0.f;
        #pragma unroll 4
        for (int b = 0; b < 256; b += 4) {
            const float4 g = *(const float4*)&wgrow[b];
            w = fmaf(g.x, W1[(b + 0) * 128 + col], w);
            w = fmaf(g.y, W1[(b + 1) * 128 + col], w);
            w = fmaf(g.z, W1[(b + 2) * 128 + col], w);
            w = fmaf(g.w, W1[(b + 3) * 128 + col], w);
        }
        ushort h = f2bf(w);
        float hf = __uint_as_float(((uint)h) << 16);
        Bh[id] = h;
        Bl[id] = f2bf(w - hf);
    } else {
        const int id = (blockIdx.x - 128) * 256 + tid;  // < 4096
        const int j = id & 7, l = (id >> 3) & 63, ct = (id >> 9) & 1, s = id >> 10;
        const int k = s * 32 + (l >> 4) * 8 + j;
        const int col = ct * 16 + (l & 15);
        float w = W2[k * 32 + col];
        ushort h = f2bf(w);
        float hf = __uint_as_float(((uint)h) << 16);
        W2h[id] = h;
        W2l[id] = f2bf(w - hf);
    }
}

// ---------------- MFMA split-bf16 GEMM: qs = (x @ Wf) * dis[row] ------------
// R15 FIX: prefetch for step s+1 is issued AFTER the post-staging barrier and
// BEFORE the MFMA block. Previously it was issued right before __syncthreads,
// which drains vmcnt(0) -> every K-step exposed full ~900cy HBM latency with
// ZERO cover. Now the only barrier that drains it is next iter's loop-top
// barrier, with 48 MFMAs (+ multi-wave overlap) as cover.
__global__ __launch_bounds__(256) void gemm_mfma(
    const float* __restrict__ x, const ushort* __restrict__ Bh,
    const ushort* __restrict__ Bl, const float* __restrict__ dis,
    float* __restrict__ qs) {
    __shared__ __align__(16) ushort Ah[4096], Al[4096], Bhs[4096], Bls[4096];

    const int tid = threadIdx.x;
    const int w = tid >> 6, lane = tid & 63;
    const int m0 = blockIdx.x * 128;
    const int srow = tid >> 3;   // 0..31: row within 32-row staging pass
    const int skq = tid & 7;     // k-quad: covers k = skq*4 .. skq*4+3

    f32x4 acc[2][8];
    #pragma unroll
    for (int i = 0; i < 2; ++i)
        #pragma unroll
        for (int j = 0; j < 8; ++j)
            acc[i][j] = (f32x4){0.f, 0.f, 0.f, 0.f};

    float4 r0, r1, r2, r3;       // x prefetch: pass p covers rows p*32+srow
    uint4 pb0, pb1, pc0, pc1;    // B prefetch (hi: pb, lo: pc)

    auto xload = [&](int s) {
        const int kc = s * 32 + skq * 4;
        int row;
        const float4 z = make_float4(0.f, 0.f, 0.f, 0.f);
        row = m0 + srow;       r0 = (row < N_NODES) ? *(const float4*)&x[(size_t)row * 256 + kc] : z;
        row = m0 + 32 + srow;  r1 = (row < N_NODES) ? *(const float4*)&x[(size_t)row * 256 + kc] : z;
        row = m0 + 64 + srow;  r2 = (row < N_NODES) ? *(const float4*)&x[(size_t)row * 256 + kc] : z;
        row = m0 + 96 + srow;  r3 = (row < N_NODES) ? *(const float4*)&x[(size_t)row * 256 + kc] : z;
    };
    auto bload = [&](int s) {
        const uint4* ph = (const uint4*)(Bh + s * 4096);
        const uint4* pl = (const uint4*)(Bl + s * 4096);
        pb0 = ph[tid * 2]; pb1 = ph[tid * 2 + 1];
        pc0 = pl[tid * 2]; pc1 = pl[tid * 2 + 1];
    };
    auto stageA = [&](int p, const float4& v) {
        const int off = ((p * 2 + (srow >> 4)) * 64 + (skq >> 1) * 16 + (srow & 15)) * 8
                        + (skq & 1) * 4;
        ushort h0 = f2bf(v.x), h1 = f2bf(v.y), h2 = f2bf(v.z), h3 = f2bf(v.w);
        *(uint2*)&Ah[off] = make_uint2(pack2(h0, h1), pack2(h2, h3));
        float l0 = v.x - __uint_as_float(((uint)h0) << 16);
        float l1 = v.y - __uint_as_float(((uint)h1) << 16);
        float l2 = v.z - __uint_as_float(((uint)h2) << 16);
        float l3 = v.w - __uint_as_float(((uint)h3) << 16);
        *(uint2*)&Al[off] = make_uint2(pack2(f2bf(l0), f2bf(l1)),
                                       pack2(f2bf(l2), f2bf(l3)));
    };

    xload(0);
    bload(0);

    for (int s = 0; s < 8; ++s) {
        if (s) __syncthreads();   // drains prev prefetch — covered by prev MFMAs
        stageA(0, r0); stageA(1, r1); stageA(2, r2); stageA(3, r3);
        *(uint4*)&Bhs[tid * 16] = pb0; *(uint4*)&Bhs[tid * 16 + 8] = pb1;
        *(uint4*)&Bls[tid * 16] = pc0; *(uint4*)&Bls[tid * 16 + 8] = pc1;
        __syncthreads();          // staging visible (vmcnt already 0 here)
        if (s < 7) { xload(s + 1); bload(s + 1); }  // in flight across MFMAs

        const bf16x8 ah0 = *(const bf16x8*)&Ah[((w * 2 + 0) * 64 + lane) * 8];
        const bf16x8 al0 = *(const bf16x8*)&Al[((w * 2 + 0) * 64 + lane) * 8];
        const bf16x8 ah1 = *(const bf16x8*)&Ah[((w * 2 + 1) * 64 + lane) * 8];
        const bf16x8 al1 = *(const bf16x8*)&Al[((w * 2 + 1) * 64 + lane) * 8];
        #pragma unroll
        for (int ct = 0; ct < 8; ++ct) {
            const bf16x8 bh = *(const bf16x8*)&Bhs[(ct * 64 + lane) * 8];
            const bf16x8 bl = *(const bf16x8*)&Bls[(ct * 64 + lane) * 8];
            acc[0][ct] = __builtin_amdgcn_mfma_f32_16x16x32_bf16(al0, bh, acc[0][ct], 0, 0, 0);
            acc[0][ct] = __builtin_amdgcn_mfma_f32_16x16x32_bf16(ah0, bl, acc[0][ct], 0, 0, 0);
            acc[0][ct] = __builtin_amdgcn_mfma_f32_16x16x32_bf16(ah0, bh, acc[0][ct], 0, 0, 0);
            acc[1][ct] = __builtin_amdgcn_mfma_f32_16x16x32_bf16(al1, bh, acc[1][ct], 0, 0, 0);
            acc[1][ct] = __builtin_amdgcn_mfma_f32_16x16x32_bf16(ah1, bl, acc[1][ct], 0, 0, 0);
            acc[1][ct] = __builtin_amdgcn_mfma_f32_16x16x32_bf16(ah1, bh, acc[1][ct], 0, 0, 0);
        }
    }

    #pragma unroll
    for (int rt = 0; rt < 2; ++rt) {
        #pragma unroll
        for (int j = 0; j < 4; ++j) {
            const int row = m0 + w * 32 + rt * 16 + (lane >> 4) * 4 + j;
            if (row < N_NODES) {
                const float sc = dis[row];
                #pragma unroll
                for (int ct = 0; ct < 8; ++ct)
                    qs[(size_t)row * 128 + ct * 16 + (lane & 15)] = acc[rt][ct][j] * sc;
            }
        }
    }
}

// ---------------- CSR gather v4: 2 nodes/wave, float4 lanes, 8-deep ILP -----
__global__ __launch_bounds__(256) void k_gather(
    const float* __restrict__ qs, const int* __restrict__ rowptr,
    const int* __restrict__ csr, const float* __restrict__ dis,
    float* __restrict__ p) {
    int node = blockIdx.x * 8 + (threadIdx.x >> 5);  // half-wave per node
    if (node >= N_NODES) return;
    int sl = threadIdx.x & 31;                       // 32 lanes x 16B = row
    int beg = rowptr[node], end = rowptr[node + 1];
    float4 acc = *(const float4*)&qs[(size_t)node * 128 + sl * 4];
    int j = beg;
    for (; j + 8 <= end; j += 8) {
        int s0 = csr[j],     s1 = csr[j + 1], s2 = csr[j + 2], s3 = csr[j + 3];
        int s4 = csr[j + 4], s5 = csr[j + 5], s6 = csr[j + 6], s7 = csr[j + 7];
        float4 v0 = *(const float4*)&qs[(size_t)s0 * 128 + sl * 4];
        float4 v1 = *(const float4*)&qs[(size_t)s1 * 128 + sl * 4];
        float4 v2 = *(const float4*)&qs[(size_t)s2 * 128 + sl * 4];
        float4 v3 = *(const float4*)&qs[(size_t)s3 * 128 + sl * 4];
        float4 v4 = *(const float4*)&qs[(size_t)s4 * 128 + sl * 4];
        float4 v5 = *(const float4*)&qs[(size_t)s5 * 128 + sl * 4];
        float4 v6 = *(const float4*)&qs[(size_t)s6 * 128 + sl * 4];
        float4 v7 = *(const float4*)&qs[(size_t)s7 * 128 + sl * 4];
        acc.x += v0.x + v1.x + v2.x + v3.x + v4.x + v5.x + v6.x + v7.x;
        acc.y += v0.y + v1.y + v2.y + v3.y + v4.y + v5.y + v6.y + v7.y;
        acc.z += v0.z + v1.z + v2.z + v3.z + v4.z + v5.z + v6.z + v7.z;
        acc.w += v0.w + v1.w + v2.w + v3.w + v4.w + v5.w + v6.w + v7.w;
    }
    for (; j + 4 <= end; j += 4) {
        int s0 = csr[j], s1 = csr[j + 1], s2 = csr[j + 2], s3 = csr[j + 3];
        float4 v0 = *(const float4*)&qs[(size_t)s0 * 128 + sl * 4];
        float4 v1 = *(const float4*)&qs[(size_t)s1 * 128 + sl * 4];
        float4 v2 = *(const float4*)&qs[(size_t)s2 * 128 + sl * 4];
        float4 v3 = *(const float4*)&qs[(size_t)s3 * 128 + sl * 4];
        acc.x += v0.x + v1.x + v2.x + v3.x;
        acc.y += v0.y + v1.y + v2.y + v3.y;
        acc.z += v0.z + v1.z + v2.z + v3.z;
        acc.w += v0.w + v1.w + v2.w + v3.w;
    }
    for (; j < end; ++j) {
        int src = csr[j];
        float4 v = *(const float4*)&qs[(size_t)src * 128 + sl * 4];
        acc.x += v.x; acc.y += v.y; acc.z += v.z; acc.w += v.w;
    }
    float d = dis[node];
    float4 r = {acc.x * d, acc.y * d, acc.z * d, acc.w * d};
    *(float4*)&p[(size_t)node * 128 + sl * 4] = r;
}

// ---------------- fused edge MLP v7 (PROVEN 85us — v8's 8-wave seq-hi/lo
// variant regressed to 95.6us, occupancy didn't rise; do not re-try) --------
__global__ __launch_bounds__(256, 4) void k_edge_mlp(
    const float* __restrict__ p, const int* __restrict__ eli,
    const float* __restrict__ b1, const ushort* __restrict__ W2h,
    const ushort* __restrict__ W2l, const float* __restrict__ b2,
    const float* __restrict__ W3, const float* __restrict__ b3,
    float* __restrict__ out) {
    __shared__ __align__(16) ushort sth[4][2048], stl[4][2048];
    __shared__ __align__(16) ushort w2hs[4096], w2ls[4096];

    const int tid = threadIdx.x;
    const int wave = tid >> 6, lane = tid & 63;
    const int row = lane & 15;   // edge within a 16-edge batch
    const int s = lane >> 4;     // channel group: s*32 .. s*32+31

    // stage W2 fragments to LDS (once per block)
    *(uint4*)&w2hs[tid * 16]     = *(const uint4*)&W2h[tid * 16];
    *(uint4*)&w2hs[tid * 16 + 8] = *(const uint4*)&W2h[tid * 16 + 8];
    *(uint4*)&w2ls[tid * 16]     = *(const uint4*)&W2l[tid * 16];
    *(uint4*)&w2ls[tid * 16 + 8] = *(const uint4*)&W2l[tid * 16 + 8];
    __syncthreads();

    const int e0 = (blockIdx.x * 4 + wave) * 64;  // 4 batches x 16 edges

    int srcs[4], dsts[4];
    #pragma unroll
    for (int b = 0; b < 4; ++b) {
        const int eb = (e0 + b * 16 < N_LABEL) ? e0 + b * 16 : 0;
        srcs[b] = eli[eb + row];
        dsts[b] = eli[N_LABEL + eb + row];
    }

    const float b2a = b2[row];
    const float b2b = b2[16 + row];
    const float w3a = W3[row];
    const float w3b = W3[16 + row];
    const float b3r = b3[0];

    float4 pdb[2][8], psb[2][8];
    auto loadrows = [&](int b, int buf) {
        const float* prd = &p[(size_t)dsts[b] * 128 + s * 32];
        const float* prs = &p[(size_t)srcs[b] * 128 + s * 32];
        #pragma unroll
        for (int cc = 0; cc < 8; ++cc) {
            pdb[buf][cc] = *(const float4*)&prd[cc * 4];
            psb[buf][cc] = *(const float4*)&prs[cc * 4];
        }
    };

    loadrows(0, 0);

    #pragma unroll
    for (int b = 0; b < 4; ++b) {
        const int cur = b & 1;
        // layer1: t = relu(pd-ps+b1) -> hi/lo bf16 -> fragment-linear LDS
        #pragma unroll
        for (int cc = 0; cc < 8; ++cc) {
            const float4 pd = pdb[cur][cc];
            const float4 ps = psb[cur][cc];
            const float4 bb = *(const float4*)&b1[s * 32 + cc * 4];
            float t0 = fmaxf(pd.x - ps.x + bb.x, 0.f);
            float t1 = fmaxf(pd.y - ps.y + bb.y, 0.f);
            float t2 = fmaxf(pd.z - ps.z + bb.z, 0.f);
            float t3 = fmaxf(pd.w - ps.w + bb.w, 0.f);
            ushort h0 = f2bf(t0), h1 = f2bf(t1), h2 = f2bf(t2), h3 = f2bf(t3);
            const int off = (s * 64 + (cc >> 1) * 16 + row) * 8 + (cc & 1) * 4;
            *(uint2*)&sth[wave][off] = make_uint2(pack2(h0, h1), pack2(h2, h3));
            float l0 = t0 - __uint_as_float(((uint)h0) << 16);
            float l1 = t1 - __uint_as_float(((uint)h1) << 16);
            float l2 = t2 - __uint_as_float(((uint)h2) << 16);
            float l3 = t3 - __uint_as_float(((uint)h3) << 16);
            *(uint2*)&stl[wave][off] = make_uint2(pack2(f2bf(l0), f2bf(l1)),
                                                  pack2(f2bf(l2), f2bf(l3)));
        }
        // prefetch next batch's rows (flies under MFMA + epilogue below)
        if (b < 3) loadrows(b + 1, cur ^ 1);

        // layer2 on MFMA; A from per-wave LDS, B (W2) from block LDS
        f32x4 acc0 = (f32x4){0.f, 0.f, 0.f, 0.f};
        f32x4 acc1 = (f32x4){0.f, 0.f, 0.f, 0.f};
        #pragma unroll
        for (int ss = 0; ss < 4; ++ss) {
            const bf16x8 ah = *(const bf16x8*)&sth[wave][(ss * 64 + lane) * 8];
            const bf16x8 al = *(const bf16x8*)&stl[wave][(ss * 64 + lane) * 8];
            const bf16x8 bh0 = *(const bf16x8*)&w2hs[((ss * 2 + 0) * 64 + lane) * 8];
            const bf16x8 bl0 = *(const bf16x8*)&w2ls[((ss * 2 + 0) * 64 + lane) * 8];
            const bf16x8 bh1 = *(const bf16x8*)&w2hs[((ss * 2 + 1) * 64 + lane) * 8];
            const bf16x8 bl1 = *(const bf16x8*)&w2ls[((ss * 2 + 1) * 64 + lane) * 8];
            acc0 = __builtin_amdgcn_mfma_f32_16x16x32_bf16(al, bh0, acc0, 0, 0, 0);
            acc0 = __builtin_amdgcn_mfma_f32_16x16x32_bf16(ah, bl0, acc0, 0, 0, 0);
            acc0 = __builtin_amdgcn_mfma_f32_16x16x32_bf16(ah, bh0, acc0, 0, 0, 0);
            acc1 = __builtin_amdgcn_mfma_f32_16x16x32_bf16(al, bh1, acc1, 0, 0, 0);
            acc1 = __builtin_amdgcn_mfma_f32_16x16x32_bf16(ah, bl1, acc1, 0, 0, 0);
            acc1 = __builtin_amdgcn_mfma_f32_16x16x32_bf16(ah, bh1, acc1, 0, 0, 0);
        }

        // epilogue: u = relu(acc + b2); out_row = sum_col u*W3[col] + b3
        const bool wr = (e0 + b * 16) < N_LABEL;
        #pragma unroll
        for (int j = 0; j < 4; ++j) {
            float v = fmaxf(acc0[j] + b2a, 0.f) * w3a
                    + fmaxf(acc1[j] + b2b, 0.f) * w3b;
            v += __shfl_xor(v, 1);
            v += __shfl_xor(v, 2);
            v += __shfl_xor(v, 4);
            v += __shfl_xor(v, 8);
            if (wr && row == 0) out[e0 + b * 16 + s * 4 + j] = v + b3r;
        }
    }
}

// ---------------- launch ----------------
extern "C" void kernel_launch(void* const* d_in, const int* in_sizes, int n_in,
                              void* d_out, int out_size, void* d_ws, size_t ws_size,
                              hipStream_t stream) {
    const float* x   = (const float*)d_in[0];
    const int*   ei  = (const int*)d_in[1];
    const int*   eli = (const int*)d_in[2];
    const float* Wg  = (const float*)d_in[3];
    // d_in[4] = b_gcn : cancels in h[dst]-h[src], unused
    const float* W1  = (const float*)d_in[5];
    const float* b1  = (const float*)d_in[6];
    const float* W2  = (const float*)d_in[7];
    const float* b2  = (const float*)d_in[8];
    const float* W3  = (const float*)d_in[9];
    const float* b3  = (const float*)d_in[10];
    float* out = (float*)d_out;

    // ---- workspace layout (bytes), all regions disjoint & 16B-aligned ----
    char* ws = (char*)d_ws;
    float*  dis    = (float*)(ws + 0);           // 400 KB
    int*    cnt    = (int*)(ws + 524288);        // 400 KB
    int*    cursor = (int*)(ws + 1048576);       // 400 KB
    int*    rowptr = (int*)(ws + 1572864);       // 400 KB + 4
    int*    bsum   = (int*)(ws + 2000000);       // 512 B (98 ints)
    int*    csr    = (int*)(ws + 2097152);       // 3.2 MB (4 MB reserved)
    ushort* Bh     = (ushort*)(ws + 6422528);    // 64 KB
    ushort* Bl     = (ushort*)(ws + 6488064);    // 64 KB
    ushort* W2h    = (ushort*)(ws + 6553600);    // 8 KB
    ushort* W2l    = (ushort*)(ws + 6561792);    // 8 KB
    float*  qs     = (float*)(ws + 8388608);     // 51.2 MB
    float*  p      = (float*)(ws + 59588608);    // 51.2 MB

    const int NB = (N_NODES + 1023) / 1024;      // 98

    // CSR build + degree norm (cnt zeroed by async memset; cursor in k_rowptr)
    hipMemsetAsync(cnt, 0, N_NODES * sizeof(int), stream);
    k_count<<<(N_EDGES + 255) / 256, 256, 0, stream>>>(ei, cnt);
    k_bsum<<<NB, 1024, 0, stream>>>(cnt, bsum);
    k_bscan<<<1, 128, 0, stream>>>(bsum, NB);
    k_rowptr<<<NB, 1024, 0, stream>>>(cnt, bsum, rowptr, dis, cursor);
    k_fill<<<(N_EDGES + 255) / 256, 256, 0, stream>>>(ei, rowptr, cursor, csr);

    // Wf = Wg@W1 -> hi/lo split, plus W2 split (one fused kernel)
    k_wf_split<<<144, 256, 0, stream>>>(Wg, W1, W2, Bh, Bl, W2h, W2l);

    // qs = (x @ Wf) * dis[row]  via split-bf16 MFMA
    gemm_mfma<<<(N_NODES + 127) / 128, 256, 0, stream>>>(x, Bh, Bl, dis, qs);

    // p[i] = dis[i] * (qs[i] + sum_{src->i} qs[src])  (2 nodes/wave)
    k_gather<<<(N_NODES + 7) / 8, 256, 0, stream>>>(qs, rowptr, csr, dis, p);

    // fused per-edge MLP v7: 4 waves x 4 batches x 16 edges = 256 edges/block
    k_edge_mlp<<<(N_LABEL + 255) / 256, 256, 0, stream>>>(
        p, eli, b1, W2h, W2l, b2, W3, b3, out);
}